// Round 2
// baseline (1258.988 us; speedup 1.0000x reference)
//
#include <hip/hip_runtime.h>
#include <hip/hip_fp16.h>

#define BATCH   65536
#define NC      16
#define DDIM    64
#define GDIM    32
#define TILE    64

// One block = 16 waves = 16 concepts, one 64-batch tile, lane = batch.
// Phase 1: x tile staged in LDS as fp16 [b][j][d] in two j-halves (64 KB),
//          XOR-swizzled so batch-stride ds_read_b128 is conflict-light.
// Phase 2: FUSED mask+W1: h_pre is linear in m and m is linear over
//          j-halves, so accumulate hacc[32] directly from 8-wide d-octets
//          (mc[8]) — no m[64] array.
// Phase 3: ELU in place on hacc.
// Phase 4: d-SLICED epilogue (new): per round r, compute only
//          och[16] = o[r*16..r*16+16) (16x32 FMA), stage the 64 KB slice
//          [b][c][dslice] in LDS (6-bit XOR swizzle -> conflict-free
//          ds_write_b128/ds_read_b128), then store with 64B full-sector
//          segments. Peak live set = hacc[32]+och[16] ~ 56 VGPR: fits the
//          compiler's 64-VGPR/8-waves-per-EU budget with ZERO scratch.
//          (Round 1 kept o[64] live across 4 barrier rounds -> ~76 dwords
//           spilled per thread -> +312 MB HBM write, VALU inflated 4x.)
extern "C" __global__ void __launch_bounds__(1024, 4)
causal_dag_kernel(const float* __restrict__ x, const float* __restrict__ A,
                  const float* __restrict__ W1, const float* __restrict__ b1,
                  const float* __restrict__ W2, const float* __restrict__ b2,
                  float* __restrict__ out)
{
    __shared__ __align__(16) unsigned char smem_raw[65536];
    __half* xs  = (__half*)smem_raw;      // phase 1-2: 64b x 8j x 64d fp16
    float*  osf = (float*)smem_raw;       // phase 4: 64b x 16c x 16d fp32 slice

    const int t    = threadIdx.x;
    const int b0   = blockIdx.x * TILE;
    const int w    = __builtin_amdgcn_readfirstlane(t >> 6);  // concept, wave-uniform
    const int lane = t & 63;                                   // batch within tile
    const int sw   = lane & 7;

    const float* W1c = W1 + w * (GDIM * DDIM);
    const float* W2c = W2 + w * (DDIM * GDIM);
    const float* b1c = b1 + w * GDIM;
    const float* b2c = b2 + w * DDIM;

    // h_pre accumulator, folded across both j-halves and all d-octets
    float hacc[GDIM];
#pragma unroll
    for (int g = 0; g < GDIM; ++g) hacc[g] = b1c[g];

    for (int jh = 0; jh < 2; ++jh) {
        // ---- stage 8 concepts of x for the 64-batch tile, fp32->fp16 ----
#pragma unroll
        for (int p = 0; p < 8; ++p) {
            int f4 = p * 1024 + t;          // float4 index in 128 KB half-tile
            int bb = f4 >> 7;               // batch-local
            int r  = f4 & 127;
            int jp = r >> 4;                // j within half
            int d4 = r & 15;                // 4-float chunk of d
            const float4 v = *(const float4*)(
                x + ((size_t)(b0 + bb) * (NC * DDIM) + (jh * 8 + jp) * DDIM + d4 * 4));
            union { __half2 h2[2]; uint2 u; } pk;
            pk.h2[0] = __floats2half2_rn(v.x, v.y);
            pk.h2[1] = __floats2half2_rn(v.z, v.w);
            int dst = bb * 512 + jp * 64 + (((d4 >> 1) ^ (bb & 7)) << 3) + ((d4 & 1) << 2);
            *(uint2*)(xs + dst) = pk.u;
        }
        __syncthreads();

        // wave-uniform DAG column for this half (s_loads -> SGPRs)
        float a[8];
#pragma unroll
        for (int jp = 0; jp < 8; ++jp) a[jp] = A[(jh * 8 + jp) * NC + w];

        // ---- fused: mc[8] = sum_j a[j]*x[b,j,d-octet]; hacc += W1 . mc ----
        const __half* xb = xs + lane * 512;
#pragma unroll
        for (int dq = 0; dq < 8; ++dq) {
            float mc[8];
#pragma unroll
            for (int k = 0; k < 8; ++k) mc[k] = 0.f;
#pragma unroll
            for (int jp = 0; jp < 8; ++jp) {
                uint4 q = *(const uint4*)(xb + jp * 64 + ((dq ^ sw) << 3)); // ds_read_b128
                float2 f0 = __half22float2(*(__half2*)&q.x);
                float2 f1 = __half22float2(*(__half2*)&q.y);
                float2 f2 = __half22float2(*(__half2*)&q.z);
                float2 f3 = __half22float2(*(__half2*)&q.w);
                mc[0] = fmaf(a[jp], f0.x, mc[0]);
                mc[1] = fmaf(a[jp], f0.y, mc[1]);
                mc[2] = fmaf(a[jp], f1.x, mc[2]);
                mc[3] = fmaf(a[jp], f1.y, mc[3]);
                mc[4] = fmaf(a[jp], f2.x, mc[4]);
                mc[5] = fmaf(a[jp], f2.y, mc[5]);
                mc[6] = fmaf(a[jp], f3.x, mc[6]);
                mc[7] = fmaf(a[jp], f3.y, mc[7]);
            }
            const int d0 = dq * 8;
#pragma unroll
            for (int g = 0; g < GDIM; ++g) {
                float acc = hacc[g];
                acc = fmaf(W1c[g * DDIM + d0 + 0], mc[0], acc);
                acc = fmaf(W1c[g * DDIM + d0 + 1], mc[1], acc);
                acc = fmaf(W1c[g * DDIM + d0 + 2], mc[2], acc);
                acc = fmaf(W1c[g * DDIM + d0 + 3], mc[3], acc);
                acc = fmaf(W1c[g * DDIM + d0 + 4], mc[4], acc);
                acc = fmaf(W1c[g * DDIM + d0 + 5], mc[5], acc);
                acc = fmaf(W1c[g * DDIM + d0 + 6], mc[6], acc);
                acc = fmaf(W1c[g * DDIM + d0 + 7], mc[7], acc);
                hacc[g] = acc;
            }
        }
        if (jh == 0) __syncthreads();   // everyone done reading before restage
    }

    // ---- ELU in place ----
#pragma unroll
    for (int g = 0; g < GDIM; ++g)
        hacc[g] = hacc[g] > 0.f ? hacc[g] : (__expf(hacc[g]) - 1.f);

    // ---- d-sliced epilogue: 4 rounds of 16 d-values each ----
    for (int r = 0; r < 4; ++r) {
        // compute this lane's 16 outputs for d in [r*16, r*16+16)
        float och[16];
#pragma unroll
        for (int i = 0; i < 16; ++i) {
            const int d = r * 16 + i;
            float acc = b2c[d];
#pragma unroll
            for (int g = 0; g < GDIM; ++g)
                acc = fmaf(W2c[d * GDIM + g], hacc[g], acc);
            och[i] = acc;
        }
        __syncthreads();   // r=0: xs reads done; r>0: previous slice stored
        // LDS slice [b][c][dslice]: float4 slot6 = (c*4+s) ^ b (bijective,
        // bank-quad = slot%8 cycles with lane -> conflict-free b128 ops)
#pragma unroll
        for (int s = 0; s < 4; ++s) {
            const int slot = ((w << 2) + s) ^ lane;
            *(float4*)(osf + lane * 256 + (slot << 2)) = *(const float4*)(och + s * 4);
        }
        __syncthreads();
        // store slice: wave = one batch row; 16 floats per (b,c) = one full
        // 64B sector; 4 consecutive lanes cover one sector
#pragma unroll
        for (int k = 0; k < 4; ++k) {
            const int f   = k * 1024 + t;   // float4 idx in 64 KB slice
            const int b   = f >> 6;         // batch-local (wave-uniform)
            const int rem = f & 63;         // (c,s) for this lane
            const int c   = rem >> 2;
            const int s   = rem & 3;
            const float4 v = *(const float4*)(osf + b * 256 + ((rem ^ b) << 2));
            *(float4*)(out + (size_t)(b0 + b) * (NC * DDIM) + c * DDIM + r * 16 + s * 4) = v;
        }
    }
}

extern "C" void kernel_launch(void* const* d_in, const int* in_sizes, int n_in,
                              void* d_out, int out_size, void* d_ws, size_t ws_size,
                              hipStream_t stream) {
    const float* x  = (const float*)d_in[0];
    const float* A  = (const float*)d_in[1];
    const float* W1 = (const float*)d_in[2];
    const float* b1 = (const float*)d_in[3];
    const float* W2 = (const float*)d_in[4];
    const float* b2 = (const float*)d_in[5];
    float* out = (float*)d_out;

    causal_dag_kernel<<<BATCH / TILE, 1024, 0, stream>>>(x, A, W1, b1, W2, b2, out);
}

// Round 3
// 1215.839 us; speedup vs baseline: 1.0355x; 1.0355x over previous
//
#include <hip/hip_runtime.h>
#include <hip/hip_fp16.h>

#define BATCH   65536
#define NC      16
#define DDIM    64
#define GDIM    32
#define TILE    64

// One block = 16 waves = 16 concepts, one 64-batch tile, lane = batch.
//
// Round-3 restructure: weights go to LDS as fp16 and are read with
// uniform-address ds_read_b128 (broadcast, conflict-free, IN-ORDER lgkmcnt)
// instead of s_loads. Rationale: SMEM returns out-of-order, so every
// scalar-weight use forced s_waitcnt lgkmcnt(0), which also drains all
// outstanding ds_reads -> phase 2 was a serial latency chain (VALUBusy 53%
// per-CU ~= 13% real issue, 7x stall). DS reads pipeline with fine-grained
// lgkmcnt(N).
//
// LDS = 128 KB (xs 64 KB + weights 64 KB) -> 1 block/CU -> register budget
// 128/thread: m[64] lives in registers (single W1 fold, not per-jh), and
// fmaf(__half2float(w), m, acc) pattern-matches v_fma_mix_f32.
//
// x-read bank fix: old layout had 8 lanes per d-octet slot on 1024-B-stride
// rows = 8-way conflict on every phase-2 ds_read_b128. XOR the j-block with
// (lane>>3) as well: (j-block, d-slot) = (jp^hi, dq^lo) is a 6-bit bijection
// over 64 lanes -> every 16-B bank-quad hit exactly 2x = free.
extern "C" __global__ void __launch_bounds__(1024, 4)
causal_dag_kernel(const float* __restrict__ x, const float* __restrict__ A,
                  const float* __restrict__ W1, const float* __restrict__ b1,
                  const float* __restrict__ W2, const float* __restrict__ b2,
                  float* __restrict__ out)
{
    __shared__ __align__(16) unsigned char smem_raw[131072];
    __half* xs  = (__half*)smem_raw;             // x tile fp16 (64 KB), then osf
    __half* wsh = (__half*)(smem_raw + 65536);   // W1 then W2, fp16 (64 KB)
    float*  osf = (float*)smem_raw;              // epilogue: 16b x 16c x 64d fp32

    const int t    = threadIdx.x;
    const int b0   = blockIdx.x * TILE;
    const int w    = __builtin_amdgcn_readfirstlane(t >> 6);  // concept
    const int lane = t & 63;                                   // batch in tile
    const int sw   = lane & 7;           // low-lane swizzle (d-octet slot)
    const int lhi  = (lane >> 3) & 7;    // high-lane swizzle (j-block)

    const float* b1c = b1 + w * GDIM;
    const float* b2c = b2 + w * DDIM;

    float m[DDIM];
#pragma unroll
    for (int d = 0; d < DDIM; ++d) m[d] = 0.f;

    for (int jh = 0; jh < 2; ++jh) {
        // ---- stage 8 concepts of x for the 64-batch tile, fp32->fp16 ----
#pragma unroll
        for (int p = 0; p < 8; ++p) {
            int f4 = p * 1024 + t;          // float4 index in 128 KB half-tile
            int bb = f4 >> 7;               // batch-local
            int r  = f4 & 127;
            int jp = r >> 4;                // j within half
            int d4 = r & 15;                // 4-float chunk of d
            const float4 v = *(const float4*)(
                x + ((size_t)(b0 + bb) * (NC * DDIM) + (jh * 8 + jp) * DDIM + d4 * 4));
            union { __half2 h2[2]; uint2 u; } pk;
            pk.h2[0] = __floats2half2_rn(v.x, v.y);
            pk.h2[1] = __floats2half2_rn(v.z, v.w);
            int dst = bb * 512 + (jp ^ (bb >> 3)) * 64
                    + (((d4 >> 1) ^ (bb & 7)) << 3) + ((d4 & 1) << 2);
            *(uint2*)(xs + dst) = pk.u;
        }
        if (jh == 0) {
            // ---- stage W1 fp32->fp16 into wsh, layout [c][g][d] ----
#pragma unroll
            for (int p = 0; p < 8; ++p) {
                int f4 = p * 1024 + t;      // 8192 float4 = 32768 floats
                const float4 v = *(const float4*)(W1 + (size_t)f4 * 4);
                union { __half2 h2[2]; uint2 u; } pk;
                pk.h2[0] = __floats2half2_rn(v.x, v.y);
                pk.h2[1] = __floats2half2_rn(v.z, v.w);
                *(uint2*)(wsh + f4 * 4) = pk.u;
            }
        }
        __syncthreads();

        // wave-uniform DAG column for this half
        float a[8];
#pragma unroll
        for (int jp = 0; jp < 8; ++jp) a[jp] = A[(jh * 8 + jp) * NC + w];

        // ---- m[d] += A[j,c] * x[b,j,d] over this j-half ----
        const __half* xb = xs + lane * 512;
#pragma unroll
        for (int dq = 0; dq < 8; ++dq) {
            const int d0 = dq * 8;
#pragma unroll
            for (int jp = 0; jp < 8; ++jp) {
                uint4 q = *(const uint4*)(xb + (jp ^ lhi) * 64 + ((dq ^ sw) << 3));
                float2 f0 = __half22float2(*(__half2*)&q.x);
                float2 f1 = __half22float2(*(__half2*)&q.y);
                float2 f2 = __half22float2(*(__half2*)&q.z);
                float2 f3 = __half22float2(*(__half2*)&q.w);
                m[d0+0] = fmaf(a[jp], f0.x, m[d0+0]);
                m[d0+1] = fmaf(a[jp], f0.y, m[d0+1]);
                m[d0+2] = fmaf(a[jp], f1.x, m[d0+2]);
                m[d0+3] = fmaf(a[jp], f1.y, m[d0+3]);
                m[d0+4] = fmaf(a[jp], f2.x, m[d0+4]);
                m[d0+5] = fmaf(a[jp], f2.y, m[d0+5]);
                m[d0+6] = fmaf(a[jp], f3.x, m[d0+6]);
                m[d0+7] = fmaf(a[jp], f3.y, m[d0+7]);
            }
        }
        if (jh == 0) __syncthreads();   // everyone done reading before restage
    }

    // ---- h = ELU(W1 @ m + b1): W1 from LDS, uniform b128 broadcast ----
    const __half* w1w = wsh + w * (GDIM * DDIM);   // [g][d]
    float h[GDIM];
#pragma unroll
    for (int g = 0; g < GDIM; ++g) {
        float acc = b1c[g];
#pragma unroll
        for (int dq = 0; dq < 8; ++dq) {
            uint4 qw = *(const uint4*)(w1w + g * DDIM + dq * 8);  // 8 halfs
            const __half* hv = (const __half*)&qw;
            const int d0 = dq * 8;
#pragma unroll
            for (int k = 0; k < 8; ++k)
                acc = fmaf(__half2float(hv[k]), m[d0 + k], acc);  // v_fma_mix
        }
        h[g] = acc > 0.f ? acc : (__expf(acc) - 1.f);
    }

    __syncthreads();   // all waves done reading W1 region (and xs)

    // ---- stage W2 fp32->fp16 into wsh, layout [c][d][g] ----
#pragma unroll
    for (int p = 0; p < 8; ++p) {
        int f4 = p * 1024 + t;
        const float4 v = *(const float4*)(W2 + (size_t)f4 * 4);
        union { __half2 h2[2]; uint2 u; } pk;
        pk.h2[0] = __floats2half2_rn(v.x, v.y);
        pk.h2[1] = __floats2half2_rn(v.z, v.w);
        *(uint2*)(wsh + f4 * 4) = pk.u;
    }
    __syncthreads();

    // ---- o = W2 @ h + b2: W2 from LDS, uniform b128 broadcast ----
    const __half* w2w = wsh + w * (DDIM * GDIM);   // [d][g]
    __align__(16) float o[DDIM];
#pragma unroll
    for (int d = 0; d < DDIM; ++d) {
        float acc = b2c[d];
#pragma unroll
        for (int gq = 0; gq < 4; ++gq) {
            uint4 qw = *(const uint4*)(w2w + d * GDIM + gq * 8);
            const __half* hv = (const __half*)&qw;
            const int g0 = gq * 8;
#pragma unroll
            for (int k = 0; k < 8; ++k)
                acc = fmaf(__half2float(hv[k]), h[g0 + k], acc);
        }
        o[d] = acc;
    }

    // ---- epilogue: LDS transpose -> coalesced stores, 16 batches/chunk ----
    const int bl = lane & 15;     // batch-local within chunk
    const int lq = lane >> 4;     // which chunk this lane belongs to
    for (int q = 0; q < 4; ++q) {
        __syncthreads();          // xs dead (q=0) / previous chunk stored
        if (lq == q) {
#pragma unroll
            for (int d4 = 0; d4 < 16; ++d4) {
                // [bl][w][d] fp32, float4-chunk XOR-swizzled by bl
                int dst = bl * 1024 + w * 64 + ((d4 ^ bl) << 2);
                *(float4*)(osf + dst) = *(const float4*)(o + d4 * 4);
            }
        }
        __syncthreads();
        // 64 KB contiguous global region for these 16 batches
        float4* og = (float4*)(out + (size_t)(b0 + q * 16) * (NC * DDIM));
#pragma unroll
        for (int k = 0; k < 4; ++k) {
            int f  = k * 1024 + t;    // float4 idx in region; wave = 1 KB contiguous
            int bb = f >> 8;          // batch-local
            int r  = f & 255;
            int c  = r >> 4;
            int d4 = r & 15;
            og[f] = *(const float4*)(osf + bb * 1024 + c * 64 + ((d4 ^ bb) << 2));
        }
    }
}

extern "C" void kernel_launch(void* const* d_in, const int* in_sizes, int n_in,
                              void* d_out, int out_size, void* d_ws, size_t ws_size,
                              hipStream_t stream) {
    const float* x  = (const float*)d_in[0];
    const float* A  = (const float*)d_in[1];
    const float* W1 = (const float*)d_in[2];
    const float* b1 = (const float*)d_in[3];
    const float* W2 = (const float*)d_in[4];
    const float* b2 = (const float*)d_in[5];
    float* out = (float*)d_out;

    causal_dag_kernel<<<BATCH / TILE, 1024, 0, stream>>>(x, A, W1, b1, W2, b2, out);
}

// Round 4
// 1210.385 us; speedup vs baseline: 1.0402x; 1.0045x over previous
//
#include <hip/hip_runtime.h>
#include <hip/hip_fp16.h>

#define BATCH   65536
#define NC      16
#define DDIM    64
#define GDIM    32
#define TILE    64

// One block = 16 waves = 16 concepts, one 64-batch tile, lane = batch.
//
// Round-4: identical structure to round 3 (LDS fp16 weights via uniform
// ds_read_b128 broadcast, conflict-free swizzled x tile, coalesced
// epilogue) PLUS amdgpu_waves_per_eu(4,4). Rationale: 128 KB LDS already
// pins occupancy to 1 block/CU = 4 waves/EU, but the register allocator's
// heuristic still targeted 8 waves/EU -> 64 VGPRs -> m[64]/o[64] spilled
// to scratch (round-3 counters: WRITE_SIZE 1.13 GB = 4.2x output,
// VALUBusy 26%). min=max=4 waves/EU raises the cap to 128 VGPRs, matching
// the occupancy LDS enforces anyway; the full live set (~110 regs peak)
// then fits with zero scratch.
extern "C" __global__ void
__launch_bounds__(1024) __attribute__((amdgpu_waves_per_eu(4, 4)))
causal_dag_kernel(const float* __restrict__ x, const float* __restrict__ A,
                  const float* __restrict__ W1, const float* __restrict__ b1,
                  const float* __restrict__ W2, const float* __restrict__ b2,
                  float* __restrict__ out)
{
    __shared__ __align__(16) unsigned char smem_raw[131072];
    __half* xs  = (__half*)smem_raw;             // x tile fp16 (64 KB), then osf
    __half* wsh = (__half*)(smem_raw + 65536);   // W1 then W2, fp16 (64 KB)
    float*  osf = (float*)smem_raw;              // epilogue: 16b x 16c x 64d fp32

    const int t    = threadIdx.x;
    const int b0   = blockIdx.x * TILE;
    const int w    = __builtin_amdgcn_readfirstlane(t >> 6);  // concept
    const int lane = t & 63;                                   // batch in tile
    const int sw   = lane & 7;           // low-lane swizzle (d-octet slot)
    const int lhi  = (lane >> 3) & 7;    // high-lane swizzle (j-block)

    const float* b1c = b1 + w * GDIM;
    const float* b2c = b2 + w * DDIM;

    float m[DDIM];
#pragma unroll
    for (int d = 0; d < DDIM; ++d) m[d] = 0.f;

    for (int jh = 0; jh < 2; ++jh) {
        // ---- stage 8 concepts of x for the 64-batch tile, fp32->fp16 ----
#pragma unroll
        for (int p = 0; p < 8; ++p) {
            int f4 = p * 1024 + t;          // float4 index in 128 KB half-tile
            int bb = f4 >> 7;               // batch-local
            int r  = f4 & 127;
            int jp = r >> 4;                // j within half
            int d4 = r & 15;                // 4-float chunk of d
            const float4 v = *(const float4*)(
                x + ((size_t)(b0 + bb) * (NC * DDIM) + (jh * 8 + jp) * DDIM + d4 * 4));
            union { __half2 h2[2]; uint2 u; } pk;
            pk.h2[0] = __floats2half2_rn(v.x, v.y);
            pk.h2[1] = __floats2half2_rn(v.z, v.w);
            int dst = bb * 512 + (jp ^ (bb >> 3)) * 64
                    + (((d4 >> 1) ^ (bb & 7)) << 3) + ((d4 & 1) << 2);
            *(uint2*)(xs + dst) = pk.u;
        }
        if (jh == 0) {
            // ---- stage W1 fp32->fp16 into wsh, layout [c][g][d] ----
#pragma unroll
            for (int p = 0; p < 8; ++p) {
                int f4 = p * 1024 + t;      // 8192 float4 = 32768 floats
                const float4 v = *(const float4*)(W1 + (size_t)f4 * 4);
                union { __half2 h2[2]; uint2 u; } pk;
                pk.h2[0] = __floats2half2_rn(v.x, v.y);
                pk.h2[1] = __floats2half2_rn(v.z, v.w);
                *(uint2*)(wsh + f4 * 4) = pk.u;
            }
        }
        __syncthreads();

        // wave-uniform DAG column for this half
        float a[8];
#pragma unroll
        for (int jp = 0; jp < 8; ++jp) a[jp] = A[(jh * 8 + jp) * NC + w];

        // ---- m[d] += A[j,c] * x[b,j,d] over this j-half ----
        const __half* xb = xs + lane * 512;
#pragma unroll
        for (int dq = 0; dq < 8; ++dq) {
            const int d0 = dq * 8;
#pragma unroll
            for (int jp = 0; jp < 8; ++jp) {
                uint4 q = *(const uint4*)(xb + (jp ^ lhi) * 64 + ((dq ^ sw) << 3));
                float2 f0 = __half22float2(*(__half2*)&q.x);
                float2 f1 = __half22float2(*(__half2*)&q.y);
                float2 f2 = __half22float2(*(__half2*)&q.z);
                float2 f3 = __half22float2(*(__half2*)&q.w);
                m[d0+0] = fmaf(a[jp], f0.x, m[d0+0]);
                m[d0+1] = fmaf(a[jp], f0.y, m[d0+1]);
                m[d0+2] = fmaf(a[jp], f1.x, m[d0+2]);
                m[d0+3] = fmaf(a[jp], f1.y, m[d0+3]);
                m[d0+4] = fmaf(a[jp], f2.x, m[d0+4]);
                m[d0+5] = fmaf(a[jp], f2.y, m[d0+5]);
                m[d0+6] = fmaf(a[jp], f3.x, m[d0+6]);
                m[d0+7] = fmaf(a[jp], f3.y, m[d0+7]);
            }
        }
        if (jh == 0) __syncthreads();   // everyone done reading before restage
    }

    // ---- h = ELU(W1 @ m + b1): W1 from LDS, uniform b128 broadcast ----
    const __half* w1w = wsh + w * (GDIM * DDIM);   // [g][d]
    float h[GDIM];
#pragma unroll
    for (int g = 0; g < GDIM; ++g) {
        float acc = b1c[g];
#pragma unroll
        for (int dq = 0; dq < 8; ++dq) {
            uint4 qw = *(const uint4*)(w1w + g * DDIM + dq * 8);  // 8 halfs
            const __half* hv = (const __half*)&qw;
            const int d0 = dq * 8;
#pragma unroll
            for (int k = 0; k < 8; ++k)
                acc = fmaf(__half2float(hv[k]), m[d0 + k], acc);  // v_fma_mix
        }
        h[g] = acc > 0.f ? acc : (__expf(acc) - 1.f);
    }

    __syncthreads();   // all waves done reading W1 region (and xs)

    // ---- stage W2 fp32->fp16 into wsh, layout [c][d][g] ----
#pragma unroll
    for (int p = 0; p < 8; ++p) {
        int f4 = p * 1024 + t;
        const float4 v = *(const float4*)(W2 + (size_t)f4 * 4);
        union { __half2 h2[2]; uint2 u; } pk;
        pk.h2[0] = __floats2half2_rn(v.x, v.y);
        pk.h2[1] = __floats2half2_rn(v.z, v.w);
        *(uint2*)(wsh + f4 * 4) = pk.u;
    }
    __syncthreads();

    // ---- o = W2 @ h + b2: W2 from LDS, uniform b128 broadcast ----
    const __half* w2w = wsh + w * (DDIM * GDIM);   // [d][g]
    __align__(16) float o[DDIM];
#pragma unroll
    for (int d = 0; d < DDIM; ++d) {
        float acc = b2c[d];
#pragma unroll
        for (int gq = 0; gq < 4; ++gq) {
            uint4 qw = *(const uint4*)(w2w + d * GDIM + gq * 8);
            const __half* hv = (const __half*)&qw;
            const int g0 = gq * 8;
#pragma unroll
            for (int k = 0; k < 8; ++k)
                acc = fmaf(__half2float(hv[k]), h[g0 + k], acc);
        }
        o[d] = acc;
    }

    // ---- epilogue: LDS transpose -> coalesced stores, 16 batches/chunk ----
    const int bl = lane & 15;     // batch-local within chunk
    const int lq = lane >> 4;     // which chunk this lane belongs to
    for (int q = 0; q < 4; ++q) {
        __syncthreads();          // xs dead (q=0) / previous chunk stored
        if (lq == q) {
#pragma unroll
            for (int d4 = 0; d4 < 16; ++d4) {
                // [bl][w][d] fp32, float4-chunk XOR-swizzled by bl
                int dst = bl * 1024 + w * 64 + ((d4 ^ bl) << 2);
                *(float4*)(osf + dst) = *(const float4*)(o + d4 * 4);
            }
        }
        __syncthreads();
        // 64 KB contiguous global region for these 16 batches
        float4* og = (float4*)(out + (size_t)(b0 + q * 16) * (NC * DDIM));
#pragma unroll
        for (int k = 0; k < 4; ++k) {
            int f  = k * 1024 + t;    // float4 idx in region; wave = 1 KB contiguous
            int bb = f >> 8;          // batch-local
            int r  = f & 255;
            int c  = r >> 4;
            int d4 = r & 15;
            og[f] = *(const float4*)(osf + bb * 1024 + c * 64 + ((d4 ^ bb) << 2));
        }
    }
}

extern "C" void kernel_launch(void* const* d_in, const int* in_sizes, int n_in,
                              void* d_out, int out_size, void* d_ws, size_t ws_size,
                              hipStream_t stream) {
    const float* x  = (const float*)d_in[0];
    const float* A  = (const float*)d_in[1];
    const float* W1 = (const float*)d_in[2];
    const float* b1 = (const float*)d_in[3];
    const float* W2 = (const float*)d_in[4];
    const float* b2 = (const float*)d_in[5];
    float* out = (float*)d_out;

    causal_dag_kernel<<<BATCH / TILE, 1024, 0, stream>>>(x, A, W1, b1, W2, b2, out);
}